// Round 1
// baseline (311.835 us; speedup 1.0000x reference)
//
#include <hip/hip_runtime.h>

#define D 64

// ---------- degree ----------
__global__ void k_deg_init(int* deg, int n) {
    int i = blockIdx.x * blockDim.x + threadIdx.x;
    if (i < n) deg[i] = 1;  // self-loop
}

__global__ void k_deg_count(const int* dst, int E, int* deg) {
    int e = blockIdx.x * blockDim.x + threadIdx.x;
    if (e < E) atomicAdd(&deg[dst[e]], 1);
}

// dinv[v] = rsqrt(deg[v]); agg[v][d] = x[v][d] * dinv[v]^2   (self-loop term)
__global__ void k_dinv_agginit(const int* deg, const float* x, float* dinv,
                               float* agg, int n) {
    int idx = blockIdx.x * blockDim.x + threadIdx.x;
    if (idx >= n * D) return;
    int v = idx >> 6;
    int d = idx & 63;
    float dv = rsqrtf((float)deg[v]);
    if (d == 0) dinv[v] = dv;
    agg[idx] = x[idx] * dv * dv;
}

// ---------- layer-1 edge scatter: wave per edge ----------
__global__ void k_edge_scatter64(const int* __restrict__ src, const int* __restrict__ dst,
                                 int E, const float* __restrict__ x,
                                 const float* __restrict__ dinv, float* agg) {
    long long t = (long long)blockIdx.x * blockDim.x + threadIdx.x;
    int e = (int)(t >> 6);
    if (e >= E) return;
    int d = (int)(t & 63);
    int u = src[e];
    int v = dst[e];
    float nrm = dinv[u] * dinv[v];
    atomicAdd(&agg[(long long)v * D + d], x[(long long)u * D + d] * nrm);
}

// ---------- fused GEMM + bias + relu + W2 projection -> s[v] ----------
__global__ __launch_bounds__(256) void k_gemm_s(const float* __restrict__ agg,
                                                const float* __restrict__ W1,
                                                const float* __restrict__ b1,
                                                const float* __restrict__ W2,
                                                float* s, int n) {
    __shared__ float lW1[D * D];
    __shared__ float lrow[4][D];
    int tid = threadIdx.x;
    for (int i = tid; i < D * D; i += 256) lW1[i] = W1[i];
    int wave = tid >> 6;
    int lane = tid & 63;
    int v = blockIdx.x * 4 + wave;
    if (v < n) lrow[wave][lane] = agg[(long long)v * D + lane];
    __syncthreads();
    if (v >= n) return;
    float acc = b1[lane];
#pragma unroll
    for (int d2 = 0; d2 < D; ++d2) acc += lrow[wave][d2] * lW1[d2 * D + lane];
    acc = fmaxf(acc, 0.0f);          // relu
    float t = acc * W2[lane];        // h1[v][lane] * W2[lane]
    // wave-wide sum (64 lanes)
#pragma unroll
    for (int off = 32; off >= 1; off >>= 1) t += __shfl_xor(t, off, 64);
    if (lane == 0) s[v] = t;
}

// ---------- layer-2 ----------
__global__ void k_out_init(const float* s, const float* dinv, const float* b2,
                           float* out, int n) {
    int v = blockIdx.x * blockDim.x + threadIdx.x;
    if (v < n) out[v] = b2[0] + s[v] * dinv[v] * dinv[v];  // bias + self-loop
}

__global__ void k_edge_scatter1(const int* __restrict__ src, const int* __restrict__ dst,
                                int E, const float* __restrict__ s,
                                const float* __restrict__ dinv, float* out) {
    int e = blockIdx.x * blockDim.x + threadIdx.x;
    if (e >= E) return;
    int u = src[e];
    int v = dst[e];
    atomicAdd(&out[v], s[u] * dinv[u] * dinv[v]);
}

extern "C" void kernel_launch(void* const* d_in, const int* in_sizes, int n_in,
                              void* d_out, int out_size, void* d_ws, size_t ws_size,
                              hipStream_t stream) {
    const float* x  = (const float*)d_in[0];
    const int*   ei = (const int*)d_in[1];
    const float* W1 = (const float*)d_in[2];
    const float* b1 = (const float*)d_in[3];
    const float* W2 = (const float*)d_in[4];
    const float* b2 = (const float*)d_in[5];

    int n = in_sizes[0] / D;     // 50000
    int E = in_sizes[1] / 2;     // 800000
    const int* src = ei;         // edge_index[0]
    const int* dst = ei + E;     // edge_index[1]

    // workspace layout (all 256B-aligned)
    char* ws = (char*)d_ws;
    auto take = [&](size_t bytes) {
        char* p = ws;
        ws += (bytes + 255) & ~(size_t)255;
        return p;
    };
    int*   deg  = (int*)take((size_t)n * sizeof(int));
    float* dinv = (float*)take((size_t)n * sizeof(float));
    float* s    = (float*)take((size_t)n * sizeof(float));
    float* agg  = (float*)take((size_t)n * D * sizeof(float));

    float* out = (float*)d_out;

    const int B = 256;

    k_deg_init<<<(n + B - 1) / B, B, 0, stream>>>(deg, n);
    k_deg_count<<<(E + B - 1) / B, B, 0, stream>>>(dst, E, deg);
    k_dinv_agginit<<<((size_t)n * D + B - 1) / B, B, 0, stream>>>(deg, x, dinv, agg, n);

    long long tot = (long long)E * D;
    k_edge_scatter64<<<(int)((tot + B - 1) / B), B, 0, stream>>>(src, dst, E, x, dinv, agg);

    k_gemm_s<<<(n + 3) / 4, B, 0, stream>>>(agg, W1, b1, W2, s, n);

    k_out_init<<<(n + B - 1) / B, B, 0, stream>>>(s, dinv, b2, out, n);
    k_edge_scatter1<<<(E + B - 1) / B, B, 0, stream>>>(src, dst, E, s, dinv, out);
}

// Round 2
// 283.490 us; speedup vs baseline: 1.1000x; 1.1000x over previous
//
#include <hip/hip_runtime.h>

#define D 64

// ---------- degree (with self-loop) ----------
__global__ void k_deg_init(int* deg, int n) {
    int i = blockIdx.x * blockDim.x + threadIdx.x;
    if (i < n) deg[i] = 1;
}

__global__ void k_deg_count(const int* __restrict__ dst, int E, int* deg) {
    int e = blockIdx.x * blockDim.x + threadIdx.x;
    if (e < E) atomicAdd(&deg[dst[e]], 1);
}

__global__ void k_dinv(const int* __restrict__ deg, float* dinv, int n) {
    int v = blockIdx.x * blockDim.x + threadIdx.x;
    if (v < n) dinv[v] = rsqrtf((float)deg[v]);
}

// ---------- exclusive scan of in-edge counts (deg-1) -> row_ptr[0..n] ----------
// single block, 1024 threads, each handles a contiguous chunk
__global__ __launch_bounds__(1024) void k_scan(const int* __restrict__ deg, int n,
                                               int* row_ptr, int* cursor) {
    __shared__ int sums[1024];
    int t = threadIdx.x;
    int chunk = (n + 1023) >> 10;
    int beg = t * chunk;
    int end = min(beg + chunk, n);
    int s = 0;
    for (int i = beg; i < end; ++i) s += deg[i] - 1;
    sums[t] = s;
    __syncthreads();
    // Hillis-Steele inclusive scan
    for (int off = 1; off < 1024; off <<= 1) {
        int v = (t >= off) ? sums[t - off] : 0;
        __syncthreads();
        sums[t] += v;
        __syncthreads();
    }
    int excl = (t == 0) ? 0 : sums[t - 1];
    for (int i = beg; i < end; ++i) {
        row_ptr[i] = excl;
        cursor[i] = 0;
        excl += deg[i] - 1;
    }
    if (t == 1023) row_ptr[n] = excl;  // total = E
}

// ---------- bucket edges by dst: csr_src[row_ptr[v] ...] = src ids ----------
__global__ void k_bucket(const int* __restrict__ src, const int* __restrict__ dst,
                         int E, const int* __restrict__ row_ptr, int* cursor,
                         int* csr_src) {
    int e = blockIdx.x * blockDim.x + threadIdx.x;
    if (e >= E) return;
    int v = dst[e];
    int pos = row_ptr[v] + atomicAdd(&cursor[v], 1);
    csr_src[pos] = src[e];
}

// ---------- fused: gather agg row (regs) -> GEMM(W1)+b1 -> relu -> dot W2 ----------
// 4 waves / block, one node per wave; writes sd[v] = s[v]*dinv[v]
__global__ __launch_bounds__(256) void k_gather_gemm(
        const float* __restrict__ x, const float* __restrict__ dinv,
        const int* __restrict__ row_ptr, const int* __restrict__ csr_src,
        const float* __restrict__ W1, const float* __restrict__ b1,
        const float* __restrict__ W2, float* sd, int n) {
    __shared__ float lW1[D * D];
    __shared__ float lrow[4][D];
    int tid = threadIdx.x;
    for (int i = tid; i < D * D; i += 256) lW1[i] = W1[i];

    int wave = tid >> 6;
    int lane = tid & 63;
    int v = blockIdx.x * 4 + wave;
    bool valid = v < n;

    float dv = 0.0f, acc = 0.0f;
    int beg = 0, end = 0;
    if (valid) {
        dv = dinv[v];
        acc = x[(size_t)v * D + lane] * dv * dv;  // self-loop term
        beg = row_ptr[v];
        end = row_ptr[v + 1];
    }
    // gather in groups of 64 edges; lane i holds edge (base+i), broadcast via shfl
    for (int base = beg; base < end; base += 64) {
        int idx = base + lane;
        int u = 0;
        float du = 0.0f;
        if (idx < end) {
            u = csr_src[idx];
            du = dinv[u];
        }
        int cnt = min(64, end - base);
        for (int i = 0; i < cnt; ++i) {
            int ui = __shfl(u, i, 64);
            float nrm = __shfl(du, i, 64) * dv;
            acc += x[(size_t)ui * D + lane] * nrm;
        }
    }
    lrow[wave][lane] = acc;
    __syncthreads();  // all waves reach exactly once

    if (!valid) return;
    float hacc = b1[lane];
#pragma unroll
    for (int d2 = 0; d2 < D; ++d2) hacc += lrow[wave][d2] * lW1[d2 * D + lane];
    hacc = fmaxf(hacc, 0.0f);      // relu
    float t = hacc * W2[lane];
#pragma unroll
    for (int off = 32; off >= 1; off >>= 1) t += __shfl_xor(t, off, 64);
    if (lane == 0) sd[v] = t * dv;  // pre-multiply by dinv[v]
}

// ---------- layer-2: per-thread gather over CSR ----------
__global__ void k_out(const float* __restrict__ sd, const float* __restrict__ dinv,
                      const int* __restrict__ row_ptr, const int* __restrict__ csr_src,
                      const float* __restrict__ b2, float* out, int n) {
    int v = blockIdx.x * blockDim.x + threadIdx.x;
    if (v >= n) return;
    float a = sd[v];  // self-loop: sd[v] = s[v]*dinv[v]
    int beg = row_ptr[v], end = row_ptr[v + 1];
    for (int i = beg; i < end; ++i) a += sd[csr_src[i]];
    out[v] = b2[0] + a * dinv[v];
}

extern "C" void kernel_launch(void* const* d_in, const int* in_sizes, int n_in,
                              void* d_out, int out_size, void* d_ws, size_t ws_size,
                              hipStream_t stream) {
    const float* x  = (const float*)d_in[0];
    const int*   ei = (const int*)d_in[1];
    const float* W1 = (const float*)d_in[2];
    const float* b1 = (const float*)d_in[3];
    const float* W2 = (const float*)d_in[4];
    const float* b2 = (const float*)d_in[5];

    int n = in_sizes[0] / D;   // 50000
    int E = in_sizes[1] / 2;   // 800000
    const int* src = ei;
    const int* dst = ei + E;

    char* ws = (char*)d_ws;
    auto take = [&](size_t bytes) {
        char* p = ws;
        ws += (bytes + 255) & ~(size_t)255;
        return p;
    };
    int*   deg     = (int*)take((size_t)n * sizeof(int));
    float* dinv    = (float*)take((size_t)n * sizeof(float));
    float* sd      = (float*)take((size_t)n * sizeof(float));
    int*   row_ptr = (int*)take((size_t)(n + 1) * sizeof(int));
    int*   cursor  = (int*)take((size_t)n * sizeof(int));
    int*   csr_src = (int*)take((size_t)E * sizeof(int));

    float* out = (float*)d_out;
    const int B = 256;

    k_deg_init<<<(n + B - 1) / B, B, 0, stream>>>(deg, n);
    k_deg_count<<<(E + B - 1) / B, B, 0, stream>>>(dst, E, deg);
    k_dinv<<<(n + B - 1) / B, B, 0, stream>>>(deg, dinv, n);
    k_scan<<<1, 1024, 0, stream>>>(deg, n, row_ptr, cursor);
    k_bucket<<<(E + B - 1) / B, B, 0, stream>>>(src, dst, E, row_ptr, cursor, csr_src);

    k_gather_gemm<<<(n + 3) / 4, B, 0, stream>>>(x, dinv, row_ptr, csr_src,
                                                 W1, b1, W2, sd, n);
    k_out<<<(n + B - 1) / B, B, 0, stream>>>(sd, dinv, row_ptr, csr_src, b2, out, n);
}

// Round 3
// 187.191 us; speedup vs baseline: 1.6659x; 1.5144x over previous
//
#include <hip/hip_runtime.h>

#define D 64

// ---------- degree (with self-loop) ----------
__global__ void k_deg_init(int* deg, int n) {
    int i = blockIdx.x * blockDim.x + threadIdx.x;
    if (i < n) deg[i] = 1;
}

__global__ void k_deg_count(const int* __restrict__ dst, int E, int* deg) {
    int e = blockIdx.x * blockDim.x + threadIdx.x;
    if (e < E) atomicAdd(&deg[dst[e]], 1);
}

__global__ void k_dinv(const int* __restrict__ deg, float* dinv, int n) {
    int v = blockIdx.x * blockDim.x + threadIdx.x;
    if (v < n) dinv[v] = rsqrtf((float)deg[v]);
}

// ---------- 3-phase device-wide exclusive scan of (deg-1) -> row_ptr ----------
// phase 1: per-block sums
__global__ __launch_bounds__(256) void k_scan_partial(const int* __restrict__ deg,
                                                      int n, int* __restrict__ bsum) {
    __shared__ int red[256];
    int t = threadIdx.x;
    int i = blockIdx.x * 256 + t;
    red[t] = (i < n) ? deg[i] - 1 : 0;
    __syncthreads();
    for (int off = 128; off >= 1; off >>= 1) {
        if (t < off) red[t] += red[t + off];
        __syncthreads();
    }
    if (t == 0) bsum[blockIdx.x] = red[0];
}

// phase 2: single small block scans the block sums in-place (nb <= 256)
__global__ __launch_bounds__(256) void k_scan_bsum(int* bsum, int nb) {
    __shared__ int sh[256];
    int t = threadIdx.x;
    sh[t] = (t < nb) ? bsum[t] : 0;
    __syncthreads();
    for (int off = 1; off < 256; off <<= 1) {
        int v = (t >= off) ? sh[t - off] : 0;
        __syncthreads();
        sh[t] += v;
        __syncthreads();
    }
    if (t < nb) bsum[t] = (t == 0) ? 0 : sh[t - 1];
}

// phase 3: intra-block exclusive scan + block offset -> row_ptr, zero cursor
__global__ __launch_bounds__(256) void k_scan_final(const int* __restrict__ deg, int n,
                                                    const int* __restrict__ bsum,
                                                    int* row_ptr, int* cursor) {
    __shared__ int sh[256];
    int t = threadIdx.x;
    int i = blockIdx.x * 256 + t;
    int val = (i < n) ? deg[i] - 1 : 0;
    sh[t] = val;
    __syncthreads();
    for (int off = 1; off < 256; off <<= 1) {
        int v = (t >= off) ? sh[t - off] : 0;
        __syncthreads();
        sh[t] += v;
        __syncthreads();
    }
    int excl = bsum[blockIdx.x] + sh[t] - val;  // exclusive prefix
    if (i < n) {
        row_ptr[i] = excl;
        cursor[i] = 0;
    }
    if (i == n - 1) row_ptr[n] = excl + val;  // total = E
}

// ---------- bucket edges by dst: csr_src[row_ptr[v] ...] = src ids ----------
__global__ void k_bucket(const int* __restrict__ src, const int* __restrict__ dst,
                         int E, const int* __restrict__ row_ptr, int* cursor,
                         int* csr_src) {
    int e = blockIdx.x * blockDim.x + threadIdx.x;
    if (e >= E) return;
    int v = dst[e];
    int pos = row_ptr[v] + atomicAdd(&cursor[v], 1);
    csr_src[pos] = src[e];
}

// ---------- fused: gather agg row (regs) -> GEMM(W1)+b1 -> relu -> dot W2 ----------
// 4 waves / block, one node per wave; writes sd[v] = s[v]*dinv[v]
__global__ __launch_bounds__(256) void k_gather_gemm(
        const float* __restrict__ x, const float* __restrict__ dinv,
        const int* __restrict__ row_ptr, const int* __restrict__ csr_src,
        const float* __restrict__ W1, const float* __restrict__ b1,
        const float* __restrict__ W2, float* sd, int n) {
    __shared__ float lW1[D * D];
    __shared__ float lrow[4][D];
    int tid = threadIdx.x;
    for (int i = tid; i < D * D; i += 256) lW1[i] = W1[i];

    int wave = tid >> 6;
    int lane = tid & 63;
    int v = blockIdx.x * 4 + wave;
    bool valid = v < n;

    float dv = 0.0f, acc = 0.0f;
    int beg = 0, end = 0;
    if (valid) {
        dv = dinv[v];
        acc = x[(size_t)v * D + lane] * dv * dv;  // self-loop term
        beg = row_ptr[v];
        end = row_ptr[v + 1];
    }
    // gather in groups of 64 edges; lane i holds edge (base+i), broadcast via shfl
    for (int base = beg; base < end; base += 64) {
        int idx = base + lane;
        int u = 0;
        float du = 0.0f;
        if (idx < end) {
            u = csr_src[idx];
            du = dinv[u];
        }
        int cnt = min(64, end - base);
        for (int i = 0; i < cnt; ++i) {
            int ui = __shfl(u, i, 64);
            float nrm = __shfl(du, i, 64) * dv;
            acc += x[(size_t)ui * D + lane] * nrm;
        }
    }
    lrow[wave][lane] = acc;
    __syncthreads();  // all waves reach exactly once

    if (!valid) return;
    float hacc = b1[lane];
#pragma unroll
    for (int d2 = 0; d2 < D; ++d2) hacc += lrow[wave][d2] * lW1[d2 * D + lane];
    hacc = fmaxf(hacc, 0.0f);      // relu
    float t = hacc * W2[lane];
#pragma unroll
    for (int off = 32; off >= 1; off >>= 1) t += __shfl_xor(t, off, 64);
    if (lane == 0) sd[v] = t * dv;  // pre-multiply by dinv[v]
}

// ---------- layer-2: per-thread gather over CSR ----------
__global__ void k_out(const float* __restrict__ sd, const float* __restrict__ dinv,
                      const int* __restrict__ row_ptr, const int* __restrict__ csr_src,
                      const float* __restrict__ b2, float* out, int n) {
    int v = blockIdx.x * blockDim.x + threadIdx.x;
    if (v >= n) return;
    float a = sd[v];  // self-loop: sd[v] = s[v]*dinv[v]
    int beg = row_ptr[v], end = row_ptr[v + 1];
    for (int i = beg; i < end; ++i) a += sd[csr_src[i]];
    out[v] = b2[0] + a * dinv[v];
}

extern "C" void kernel_launch(void* const* d_in, const int* in_sizes, int n_in,
                              void* d_out, int out_size, void* d_ws, size_t ws_size,
                              hipStream_t stream) {
    const float* x  = (const float*)d_in[0];
    const int*   ei = (const int*)d_in[1];
    const float* W1 = (const float*)d_in[2];
    const float* b1 = (const float*)d_in[3];
    const float* W2 = (const float*)d_in[4];
    const float* b2 = (const float*)d_in[5];

    int n = in_sizes[0] / D;   // 50000
    int E = in_sizes[1] / 2;   // 800000
    const int* src = ei;
    const int* dst = ei + E;

    char* ws = (char*)d_ws;
    auto take = [&](size_t bytes) {
        char* p = ws;
        ws += (bytes + 255) & ~(size_t)255;
        return p;
    };
    int nb = (n + 255) / 256;  // 196 blocks for the scan
    int*   deg     = (int*)take((size_t)n * sizeof(int));
    float* dinv    = (float*)take((size_t)n * sizeof(float));
    float* sd      = (float*)take((size_t)n * sizeof(float));
    int*   row_ptr = (int*)take((size_t)(n + 1) * sizeof(int));
    int*   cursor  = (int*)take((size_t)n * sizeof(int));
    int*   bsum    = (int*)take((size_t)nb * sizeof(int));
    int*   csr_src = (int*)take((size_t)E * sizeof(int));

    float* out = (float*)d_out;
    const int B = 256;

    k_deg_init<<<(n + B - 1) / B, B, 0, stream>>>(deg, n);
    k_deg_count<<<(E + B - 1) / B, B, 0, stream>>>(dst, E, deg);
    k_dinv<<<(n + B - 1) / B, B, 0, stream>>>(deg, dinv, n);

    k_scan_partial<<<nb, 256, 0, stream>>>(deg, n, bsum);
    k_scan_bsum<<<1, 256, 0, stream>>>(bsum, nb);
    k_scan_final<<<nb, 256, 0, stream>>>(deg, n, bsum, row_ptr, cursor);

    k_bucket<<<(E + B - 1) / B, B, 0, stream>>>(src, dst, E, row_ptr, cursor, csr_src);

    k_gather_gemm<<<(n + 3) / 4, B, 0, stream>>>(x, dinv, row_ptr, csr_src,
                                                 W1, b1, W2, sd, n);
    k_out<<<(n + B - 1) / B, B, 0, stream>>>(sd, dinv, row_ptr, csr_src, b2, out, n);
}

// Round 4
// 171.029 us; speedup vs baseline: 1.8233x; 1.0945x over previous
//
#include <hip/hip_runtime.h>

#define D 64

// ---------- in-degree count (no self-loop; deg[] pre-zeroed by memset) ----------
__global__ void k_deg_count(const int* __restrict__ dst, int E, int* deg) {
    int e = blockIdx.x * blockDim.x + threadIdx.x;
    if (e < E) atomicAdd(&deg[dst[e]], 1);
}

// ---------- scan phase 1: per-block sums of deg; also dinv = rsqrt(deg+1) ----------
__global__ __launch_bounds__(256) void k_scan_partial(const int* __restrict__ deg,
                                                      int n, int* __restrict__ bsum,
                                                      float* __restrict__ dinv) {
    __shared__ int red[256];
    int t = threadIdx.x;
    int i = blockIdx.x * 256 + t;
    int d = (i < n) ? deg[i] : 0;
    if (i < n) dinv[i] = rsqrtf((float)(d + 1));  // +1 = self-loop
    red[t] = d;
    __syncthreads();
    for (int off = 128; off >= 1; off >>= 1) {
        if (t < off) red[t] += red[t + off];
        __syncthreads();
    }
    if (t == 0) bsum[blockIdx.x] = red[0];
}

// ---------- scan phase 2: one small block scans block sums (nb <= 256) ----------
__global__ __launch_bounds__(256) void k_scan_bsum(int* bsum, int nb) {
    __shared__ int sh[256];
    int t = threadIdx.x;
    sh[t] = (t < nb) ? bsum[t] : 0;
    __syncthreads();
    for (int off = 1; off < 256; off <<= 1) {
        int v = (t >= off) ? sh[t - off] : 0;
        __syncthreads();
        sh[t] += v;
        __syncthreads();
    }
    if (t < nb) bsum[t] = (t == 0) ? 0 : sh[t - 1];
}

// ---------- scan phase 3: row_ptr + zero cursor ----------
__global__ __launch_bounds__(256) void k_scan_final(const int* __restrict__ deg, int n,
                                                    const int* __restrict__ bsum,
                                                    int* row_ptr, int* cursor) {
    __shared__ int sh[256];
    int t = threadIdx.x;
    int i = blockIdx.x * 256 + t;
    int val = (i < n) ? deg[i] : 0;
    sh[t] = val;
    __syncthreads();
    for (int off = 1; off < 256; off <<= 1) {
        int v = (t >= off) ? sh[t - off] : 0;
        __syncthreads();
        sh[t] += v;
        __syncthreads();
    }
    int excl = bsum[blockIdx.x] + sh[t] - val;
    if (i < n) {
        row_ptr[i] = excl;
        cursor[i] = 0;
    }
    if (i == n - 1) row_ptr[n] = excl + val;  // = E
}

// ---------- bucket: csr_ud[pos] = {src, norm = dinv[u]*dinv[v]} ----------
__global__ void k_bucket(const int* __restrict__ src, const int* __restrict__ dst,
                         int E, const int* __restrict__ row_ptr, int* cursor,
                         const float* __restrict__ dinv, int2* __restrict__ csr_ud) {
    int e = blockIdx.x * blockDim.x + threadIdx.x;
    if (e >= E) return;
    int u = src[e];
    int v = dst[e];
    float nrm = dinv[u] * dinv[v];
    int pos = row_ptr[v] + atomicAdd(&cursor[v], 1);
    csr_ud[pos] = make_int2(u, __float_as_int(nrm));
}

// ---------- fused gather + GEMM + relu + W2-dot ----------
// wave = 4 edges x 16 dim-groups; 8 nodes per wave; W1 column in VGPRs.
__global__ __launch_bounds__(256) void k_gather_gemm(
        const float* __restrict__ x, const float* __restrict__ dinv,
        const int* __restrict__ row_ptr, const int2* __restrict__ csr_ud,
        const float* __restrict__ W1, const float* __restrict__ b1,
        const float* __restrict__ W2, float* __restrict__ sd, int n) {
    __shared__ float lrow[4][D];
    int tid = threadIdx.x;
    int wave = tid >> 6, lane = tid & 63;
    int eg = lane >> 4, dg = lane & 15;

    // W1 column `lane` into registers (coalesced row loads), amortized over 8 nodes
    float w1c[D];
#pragma unroll
    for (int d = 0; d < D; ++d) w1c[d] = W1[d * D + lane];
    float b1l = b1[lane];
    float w2l = W2[lane];

    int v0 = (blockIdx.x * 4 + wave) * 8;
    for (int k = 0; k < 8; ++k) {
        int v = v0 + k;          // wave-uniform
        if (v >= n) break;
        float dv = dinv[v];
        int beg = row_ptr[v], end = row_ptr[v + 1];

        float4 acc = make_float4(0.f, 0.f, 0.f, 0.f);
        if (eg == 0) {           // self-loop term
            float4 xv = *(const float4*)&x[(size_t)v * D + dg * 4];
            float w = dv * dv;
            acc.x = xv.x * w; acc.y = xv.y * w; acc.z = xv.z * w; acc.w = xv.w * w;
        }
        // 4 edges in parallel, 16 dims (float4) per lane — no shuffles in the loop
        for (int base = beg; base < end; base += 4) {
            int idx = base + eg;
            if (idx < end) {
                int2 e = csr_ud[idx];
                float nrm = __int_as_float(e.y);
                float4 xv = *(const float4*)&x[(size_t)e.x * D + dg * 4];
                acc.x += xv.x * nrm; acc.y += xv.y * nrm;
                acc.z += xv.z * nrm; acc.w += xv.w * nrm;
            }
        }
        // reduce the 4 edge-subgroups (xor 16, 32)
#pragma unroll
        for (int off = 16; off <= 32; off <<= 1) {
            acc.x += __shfl_xor(acc.x, off, 64);
            acc.y += __shfl_xor(acc.y, off, 64);
            acc.z += __shfl_xor(acc.z, off, 64);
            acc.w += __shfl_xor(acc.w, off, 64);
        }
        if (eg == 0) *(float4*)&lrow[wave][dg * 4] = acc;  // wave-private slice
        __builtin_amdgcn_wave_barrier();

        float h = b1l;
#pragma unroll
        for (int db = 0; db < D; db += 4) {
            float4 r = *(const float4*)&lrow[wave][db];    // broadcast ds_read_b128
            h = fmaf(r.x, w1c[db], h);
            h = fmaf(r.y, w1c[db + 1], h);
            h = fmaf(r.z, w1c[db + 2], h);
            h = fmaf(r.w, w1c[db + 3], h);
        }
        float tt = fmaxf(h, 0.0f) * w2l;
#pragma unroll
        for (int off = 1; off <= 32; off <<= 1) tt += __shfl_xor(tt, off, 64);
        if (lane == 0) sd[v] = tt * dv;   // s[v] * dinv[v]
        __builtin_amdgcn_wave_barrier();
    }
}

// ---------- layer-2: 4 lanes per node gather over CSR ----------
__global__ __launch_bounds__(256) void k_out(const float* __restrict__ sd,
        const float* __restrict__ dinv, const int* __restrict__ row_ptr,
        const int2* __restrict__ csr_ud, const float* __restrict__ b2,
        float* __restrict__ out, int n) {
    int t = blockIdx.x * blockDim.x + threadIdx.x;
    int v = t >> 2, r = t & 3;
    if (v >= n) return;
    int beg = row_ptr[v], end = row_ptr[v + 1];
    float a = (r == 0) ? sd[v] : 0.0f;   // self-loop
    for (int i = beg + r; i < end; i += 4) a += sd[csr_ud[i].x];
    a += __shfl_xor(a, 1, 64);
    a += __shfl_xor(a, 2, 64);
    if (r == 0) out[v] = b2[0] + a * dinv[v];
}

extern "C" void kernel_launch(void* const* d_in, const int* in_sizes, int n_in,
                              void* d_out, int out_size, void* d_ws, size_t ws_size,
                              hipStream_t stream) {
    const float* x  = (const float*)d_in[0];
    const int*   ei = (const int*)d_in[1];
    const float* W1 = (const float*)d_in[2];
    const float* b1 = (const float*)d_in[3];
    const float* W2 = (const float*)d_in[4];
    const float* b2 = (const float*)d_in[5];

    int n = in_sizes[0] / D;   // 50000
    int E = in_sizes[1] / 2;   // 800000
    const int* src = ei;
    const int* dst = ei + E;

    char* ws = (char*)d_ws;
    auto take = [&](size_t bytes) {
        char* p = ws;
        ws += (bytes + 255) & ~(size_t)255;
        return p;
    };
    int nb = (n + 255) / 256;  // 196
    int*   deg     = (int*)take((size_t)n * sizeof(int));
    float* dinv    = (float*)take((size_t)n * sizeof(float));
    float* sd      = (float*)take((size_t)n * sizeof(float));
    int*   row_ptr = (int*)take((size_t)(n + 1) * sizeof(int));
    int*   cursor  = (int*)take((size_t)n * sizeof(int));
    int*   bsum    = (int*)take((size_t)nb * sizeof(int));
    int2*  csr_ud  = (int2*)take((size_t)E * sizeof(int2));

    float* out = (float*)d_out;
    const int B = 256;

    hipMemsetAsync(deg, 0, (size_t)n * sizeof(int), stream);
    k_deg_count<<<(E + B - 1) / B, B, 0, stream>>>(dst, E, deg);

    k_scan_partial<<<nb, 256, 0, stream>>>(deg, n, bsum, dinv);
    k_scan_bsum<<<1, 256, 0, stream>>>(bsum, nb);
    k_scan_final<<<nb, 256, 0, stream>>>(deg, n, bsum, row_ptr, cursor);

    k_bucket<<<(E + B - 1) / B, B, 0, stream>>>(src, dst, E, row_ptr, cursor, dinv, csr_ud);

    int waves = (n + 7) / 8;                 // 8 nodes per wave
    int blocks = (waves + 3) / 4;            // 4 waves per block
    k_gather_gemm<<<blocks, 256, 0, stream>>>(x, dinv, row_ptr, csr_ud,
                                              W1, b1, W2, sd, n);

    k_out<<<((size_t)n * 4 + B - 1) / B, B, 0, stream>>>(sd, dinv, row_ptr, csr_ud,
                                                         b2, out, n);
}

// Round 5
// 154.594 us; speedup vs baseline: 2.0171x; 1.1063x over previous
//
#include <hip/hip_runtime.h>

#define D 64

// ---------- in-degree count: 4 edges/thread (deg pre-zeroed) ----------
__global__ void k_deg_count(const int* __restrict__ dst, int E, int* deg) {
    int i = blockIdx.x * blockDim.x + threadIdx.x;
    int e = i * 4;
    if (e + 4 <= E) {
        int4 d4 = *(const int4*)&dst[e];
        atomicAdd(&deg[d4.x], 1);
        atomicAdd(&deg[d4.y], 1);
        atomicAdd(&deg[d4.z], 1);
        atomicAdd(&deg[d4.w], 1);
    } else {
        for (; e < E; ++e) atomicAdd(&deg[dst[e]], 1);
    }
}

// ---------- scan phase 1: per-block sums of deg; also dinv = rsqrt(deg+1) ----------
__global__ __launch_bounds__(256) void k_scan_partial(const int* __restrict__ deg,
                                                      int n, int* __restrict__ bsum,
                                                      float* __restrict__ dinv) {
    __shared__ int red[256];
    int t = threadIdx.x;
    int i = blockIdx.x * 256 + t;
    int d = (i < n) ? deg[i] : 0;
    if (i < n) dinv[i] = rsqrtf((float)(d + 1));  // +1 = self-loop
    red[t] = d;
    __syncthreads();
    for (int off = 128; off >= 1; off >>= 1) {
        if (t < off) red[t] += red[t + off];
        __syncthreads();
    }
    if (t == 0) bsum[blockIdx.x] = red[0];
}

// ---------- scan phase 2: one small block scans block sums (nb <= 256) ----------
__global__ __launch_bounds__(256) void k_scan_bsum(int* bsum, int nb) {
    __shared__ int sh[256];
    int t = threadIdx.x;
    sh[t] = (t < nb) ? bsum[t] : 0;
    __syncthreads();
    for (int off = 1; off < 256; off <<= 1) {
        int v = (t >= off) ? sh[t - off] : 0;
        __syncthreads();
        sh[t] += v;
        __syncthreads();
    }
    if (t < nb) bsum[t] = (t == 0) ? 0 : sh[t - 1];
}

// ---------- scan phase 3: row_ptr + cursor (= row_ptr copy) ----------
__global__ __launch_bounds__(256) void k_scan_final(const int* __restrict__ deg, int n,
                                                    const int* __restrict__ bsum,
                                                    int* row_ptr, int* cursor) {
    __shared__ int sh[256];
    int t = threadIdx.x;
    int i = blockIdx.x * 256 + t;
    int val = (i < n) ? deg[i] : 0;
    sh[t] = val;
    __syncthreads();
    for (int off = 1; off < 256; off <<= 1) {
        int v = (t >= off) ? sh[t - off] : 0;
        __syncthreads();
        sh[t] += v;
        __syncthreads();
    }
    int excl = bsum[blockIdx.x] + sh[t] - val;
    if (i < n) {
        row_ptr[i] = excl;
        cursor[i] = excl;   // bucket uses cursor directly as append position
    }
    if (i == n - 1) row_ptr[n] = excl + val;  // = E
}

// ---------- bucket: 2 edges/thread; csr_ud[pos] = {src, norm} ----------
__global__ void k_bucket(const int* __restrict__ src, const int* __restrict__ dst,
                         int E, int* cursor, const float* __restrict__ dinv,
                         int2* __restrict__ csr_ud) {
    int i = blockIdx.x * blockDim.x + threadIdx.x;
    int e = i * 2;
    if (e >= E) return;
    int2 s2 = *(const int2*)&src[e];
    int2 d2 = *(const int2*)&dst[e];
    float nrm0 = dinv[s2.x] * dinv[d2.x];
    int p0 = atomicAdd(&cursor[d2.x], 1);
    csr_ud[p0] = make_int2(s2.x, __float_as_int(nrm0));
    if (e + 1 < E) {
        float nrm1 = dinv[s2.y] * dinv[d2.y];
        int p1 = atomicAdd(&cursor[d2.y], 1);
        csr_ud[p1] = make_int2(s2.y, __float_as_int(nrm1));
    }
}

// ---------- gather: 1 node per wave, 4 edge-slots x 16 dim-groups, unroll x2 ----------
__global__ __launch_bounds__(256) void k_gather(
        const float* __restrict__ x, const float* __restrict__ dinv,
        const int* __restrict__ row_ptr, const int2* __restrict__ csr_ud,
        float* __restrict__ agg, int n) {
    int tid = threadIdx.x;
    int wave = tid >> 6, lane = tid & 63;
    int eg = lane >> 4, dg = lane & 15;
    int v = blockIdx.x * 4 + wave;
    if (v >= n) return;
    float dv = dinv[v];
    int beg = row_ptr[v], end = row_ptr[v + 1];

    float4 acc = make_float4(0.f, 0.f, 0.f, 0.f);
    if (eg == 0) {  // self-loop term
        float4 xv = *(const float4*)&x[(size_t)v * D + dg * 4];
        float w = dv * dv;
        acc.x = xv.x * w; acc.y = xv.y * w; acc.z = xv.z * w; acc.w = xv.w * w;
    }
    int base = beg;
    for (; base + 8 <= end; base += 8) {  // two independent csr->x chains
        int2 e0 = csr_ud[base + eg];
        int2 e1 = csr_ud[base + 4 + eg];
        float4 x0 = *(const float4*)&x[(size_t)e0.x * D + dg * 4];
        float4 x1 = *(const float4*)&x[(size_t)e1.x * D + dg * 4];
        float n0 = __int_as_float(e0.y), n1 = __int_as_float(e1.y);
        acc.x = fmaf(x0.x, n0, acc.x); acc.y = fmaf(x0.y, n0, acc.y);
        acc.z = fmaf(x0.z, n0, acc.z); acc.w = fmaf(x0.w, n0, acc.w);
        acc.x = fmaf(x1.x, n1, acc.x); acc.y = fmaf(x1.y, n1, acc.y);
        acc.z = fmaf(x1.z, n1, acc.z); acc.w = fmaf(x1.w, n1, acc.w);
    }
    for (; base < end; base += 4) {
        int idx = base + eg;
        if (idx < end) {
            int2 e = csr_ud[idx];
            float nrm = __int_as_float(e.y);
            float4 xv = *(const float4*)&x[(size_t)e.x * D + dg * 4];
            acc.x = fmaf(xv.x, nrm, acc.x); acc.y = fmaf(xv.y, nrm, acc.y);
            acc.z = fmaf(xv.z, nrm, acc.z); acc.w = fmaf(xv.w, nrm, acc.w);
        }
    }
#pragma unroll
    for (int off = 16; off <= 32; off <<= 1) {
        acc.x += __shfl_xor(acc.x, off, 64);
        acc.y += __shfl_xor(acc.y, off, 64);
        acc.z += __shfl_xor(acc.z, off, 64);
        acc.w += __shfl_xor(acc.w, off, 64);
    }
    if (eg == 0) *(float4*)&agg[(size_t)v * D + dg * 4] = acc;
}

// ---------- dense GEMM + relu + W2-dot: wave per node, 16 nodes/wave ----------
#define NPW 16
__global__ __launch_bounds__(256) void k_gemm(
        const float* __restrict__ agg, const float* __restrict__ dinv,
        const float* __restrict__ W1, const float* __restrict__ b1,
        const float* __restrict__ W2, float* __restrict__ sd, int n) {
    __shared__ float lrow[4][D];
    int tid = threadIdx.x;
    int wave = tid >> 6, lane = tid & 63;
    float w1c[D];
#pragma unroll
    for (int d = 0; d < D; ++d) w1c[d] = W1[d * D + lane];
    float b1l = b1[lane], w2l = W2[lane];
    int v0 = (blockIdx.x * 4 + wave) * NPW;
    for (int k = 0; k < NPW; ++k) {
        int v = v0 + k;
        if (v >= n) break;
        lrow[wave][lane] = agg[(size_t)v * D + lane];  // coalesced 256B
        __builtin_amdgcn_wave_barrier();
        float h = b1l;
#pragma unroll
        for (int db = 0; db < D; db += 4) {
            float4 r = *(const float4*)&lrow[wave][db];  // broadcast ds_read_b128
            h = fmaf(r.x, w1c[db], h);
            h = fmaf(r.y, w1c[db + 1], h);
            h = fmaf(r.z, w1c[db + 2], h);
            h = fmaf(r.w, w1c[db + 3], h);
        }
        float tt = fmaxf(h, 0.0f) * w2l;
#pragma unroll
        for (int off = 1; off <= 32; off <<= 1) tt += __shfl_xor(tt, off, 64);
        if (lane == 0) sd[v] = tt * dinv[v];  // s[v] * dinv[v]
        __builtin_amdgcn_wave_barrier();
    }
}

// ---------- layer-2: 4 lanes per node gather over CSR ----------
__global__ __launch_bounds__(256) void k_out(const float* __restrict__ sd,
        const float* __restrict__ dinv, const int* __restrict__ row_ptr,
        const int2* __restrict__ csr_ud, const float* __restrict__ b2,
        float* __restrict__ out, int n) {
    int t = blockIdx.x * blockDim.x + threadIdx.x;
    int v = t >> 2, r = t & 3;
    if (v >= n) return;
    int beg = row_ptr[v], end = row_ptr[v + 1];
    float a = (r == 0) ? sd[v] : 0.0f;  // self-loop
    for (int i = beg + r; i < end; i += 4) a += sd[csr_ud[i].x];
    a += __shfl_xor(a, 1, 64);
    a += __shfl_xor(a, 2, 64);
    if (r == 0) out[v] = b2[0] + a * dinv[v];
}

extern "C" void kernel_launch(void* const* d_in, const int* in_sizes, int n_in,
                              void* d_out, int out_size, void* d_ws, size_t ws_size,
                              hipStream_t stream) {
    const float* x  = (const float*)d_in[0];
    const int*   ei = (const int*)d_in[1];
    const float* W1 = (const float*)d_in[2];
    const float* b1 = (const float*)d_in[3];
    const float* W2 = (const float*)d_in[4];
    const float* b2 = (const float*)d_in[5];

    int n = in_sizes[0] / D;   // 50000
    int E = in_sizes[1] / 2;   // 800000
    const int* src = ei;
    const int* dst = ei + E;

    char* ws = (char*)d_ws;
    auto take = [&](size_t bytes) {
        char* p = ws;
        ws += (bytes + 255) & ~(size_t)255;
        return p;
    };
    int nb = (n + 255) / 256;  // 196
    int*   deg     = (int*)take((size_t)n * sizeof(int));
    float* dinv    = (float*)take((size_t)n * sizeof(float));
    float* sd      = (float*)take((size_t)n * sizeof(float));
    int*   row_ptr = (int*)take((size_t)(n + 1) * sizeof(int));
    int*   cursor  = (int*)take((size_t)n * sizeof(int));
    int*   bsum    = (int*)take((size_t)nb * sizeof(int));
    int2*  csr_ud  = (int2*)take((size_t)E * sizeof(int2));
    float* agg     = (float*)take((size_t)n * D * sizeof(float));

    float* out = (float*)d_out;
    const int B = 256;

    hipMemsetAsync(deg, 0, (size_t)n * sizeof(int), stream);
    k_deg_count<<<(E / 4 + B - 1) / B, B, 0, stream>>>(dst, E, deg);

    k_scan_partial<<<nb, 256, 0, stream>>>(deg, n, bsum, dinv);
    k_scan_bsum<<<1, 256, 0, stream>>>(bsum, nb);
    k_scan_final<<<nb, 256, 0, stream>>>(deg, n, bsum, row_ptr, cursor);

    k_bucket<<<((E + 1) / 2 + B - 1) / B, B, 0, stream>>>(src, dst, E, cursor,
                                                          dinv, csr_ud);

    k_gather<<<(n + 3) / 4, 256, 0, stream>>>(x, dinv, row_ptr, csr_ud, agg, n);

    k_gemm<<<(n + 4 * NPW - 1) / (4 * NPW), 256, 0, stream>>>(agg, dinv, W1, b1,
                                                              W2, sd, n);

    k_out<<<((size_t)n * 4 + B - 1) / B, B, 0, stream>>>(sd, dinv, row_ptr, csr_ud,
                                                         b2, out, n);
}

// Round 6
// 123.932 us; speedup vs baseline: 2.5162x; 1.2474x over previous
//
#include <hip/hip_runtime.h>

#define D 64

// ---------- in-degree count + per-edge rank: 4 edges/thread (deg pre-zeroed) ----------
__global__ void k_deg_count(const int* __restrict__ dst, int E, int* deg,
                            int* __restrict__ rank) {
    int i = blockIdx.x * blockDim.x + threadIdx.x;
    int e = i * 4;
    if (e + 4 <= E) {
        int4 d4 = *(const int4*)&dst[e];
        int4 r4;
        r4.x = atomicAdd(&deg[d4.x], 1);
        r4.y = atomicAdd(&deg[d4.y], 1);
        r4.z = atomicAdd(&deg[d4.z], 1);
        r4.w = atomicAdd(&deg[d4.w], 1);
        *(int4*)&rank[e] = r4;   // coalesced
    } else if (e < E) {
        for (; e < E; ++e) rank[e] = atomicAdd(&deg[dst[e]], 1);
    }
}

// ---------- scan phase 1: per-block sums of deg; also dinv = rsqrt(deg+1) ----------
__global__ __launch_bounds__(256) void k_scan_partial(const int* __restrict__ deg,
                                                      int n, int* __restrict__ bsum,
                                                      float* __restrict__ dinv) {
    __shared__ int red[256];
    int t = threadIdx.x;
    int i = blockIdx.x * 256 + t;
    int d = (i < n) ? deg[i] : 0;
    if (i < n) dinv[i] = rsqrtf((float)(d + 1));  // +1 = self-loop
    red[t] = d;
    __syncthreads();
    for (int off = 128; off >= 1; off >>= 1) {
        if (t < off) red[t] += red[t + off];
        __syncthreads();
    }
    if (t == 0) bsum[blockIdx.x] = red[0];
}

// ---------- scan phase 2: one small block scans block sums (nb <= 256) ----------
__global__ __launch_bounds__(256) void k_scan_bsum(int* bsum, int nb) {
    __shared__ int sh[256];
    int t = threadIdx.x;
    sh[t] = (t < nb) ? bsum[t] : 0;
    __syncthreads();
    for (int off = 1; off < 256; off <<= 1) {
        int v = (t >= off) ? sh[t - off] : 0;
        __syncthreads();
        sh[t] += v;
        __syncthreads();
    }
    if (t < nb) bsum[t] = (t == 0) ? 0 : sh[t - 1];
}

// ---------- scan phase 3: row_ptr ----------
__global__ __launch_bounds__(256) void k_scan_final(const int* __restrict__ deg, int n,
                                                    const int* __restrict__ bsum,
                                                    int* row_ptr) {
    __shared__ int sh[256];
    int t = threadIdx.x;
    int i = blockIdx.x * 256 + t;
    int val = (i < n) ? deg[i] : 0;
    sh[t] = val;
    __syncthreads();
    for (int off = 1; off < 256; off <<= 1) {
        int v = (t >= off) ? sh[t - off] : 0;
        __syncthreads();
        sh[t] += v;
        __syncthreads();
    }
    int excl = bsum[blockIdx.x] + sh[t] - val;
    if (i < n) row_ptr[i] = excl;
    if (i == n - 1) row_ptr[n] = excl + val;  // = E
}

// ---------- bucket: NO atomics; pos = row_ptr[dst] + rank; 2 edges/thread ----------
__global__ void k_bucket(const int* __restrict__ src, const int* __restrict__ dst,
                         const int* __restrict__ rank, int E,
                         const int* __restrict__ row_ptr, int* __restrict__ csr_src) {
    int i = blockIdx.x * blockDim.x + threadIdx.x;
    int e = i * 2;
    if (e >= E) return;
    int2 s2 = *(const int2*)&src[e];
    int2 d2 = *(const int2*)&dst[e];
    int2 r2 = *(const int2*)&rank[e];
    csr_src[row_ptr[d2.x] + r2.x] = s2.x;
    if (e + 1 < E) csr_src[row_ptr[d2.y] + r2.y] = s2.y;
}

// ---------- gather: 1 node per wave, 4 edge-slots x 16 dim-groups, unroll x2 ----------
__global__ __launch_bounds__(256) void k_gather(
        const float* __restrict__ x, const float* __restrict__ dinv,
        const int* __restrict__ row_ptr, const int* __restrict__ csr_src,
        float* __restrict__ agg, int n) {
    int tid = threadIdx.x;
    int wave = tid >> 6, lane = tid & 63;
    int eg = lane >> 4, dg = lane & 15;
    int v = blockIdx.x * 4 + wave;
    if (v >= n) return;
    float dv = dinv[v];
    int beg = row_ptr[v], end = row_ptr[v + 1];

    float4 acc = make_float4(0.f, 0.f, 0.f, 0.f);
    if (eg == 0) {  // self-loop term
        float4 xv = *(const float4*)&x[(size_t)v * D + dg * 4];
        float w = dv * dv;
        acc.x = xv.x * w; acc.y = xv.y * w; acc.z = xv.z * w; acc.w = xv.w * w;
    }
    int base = beg;
    for (; base + 8 <= end; base += 8) {  // two independent chains
        int u0 = csr_src[base + eg];
        int u1 = csr_src[base + 4 + eg];
        float n0 = dinv[u0] * dv;
        float n1 = dinv[u1] * dv;
        float4 x0 = *(const float4*)&x[(size_t)u0 * D + dg * 4];
        float4 x1 = *(const float4*)&x[(size_t)u1 * D + dg * 4];
        acc.x = fmaf(x0.x, n0, acc.x); acc.y = fmaf(x0.y, n0, acc.y);
        acc.z = fmaf(x0.z, n0, acc.z); acc.w = fmaf(x0.w, n0, acc.w);
        acc.x = fmaf(x1.x, n1, acc.x); acc.y = fmaf(x1.y, n1, acc.y);
        acc.z = fmaf(x1.z, n1, acc.z); acc.w = fmaf(x1.w, n1, acc.w);
    }
    for (; base < end; base += 4) {
        int idx = base + eg;
        if (idx < end) {
            int u = csr_src[idx];
            float nrm = dinv[u] * dv;
            float4 xv = *(const float4*)&x[(size_t)u * D + dg * 4];
            acc.x = fmaf(xv.x, nrm, acc.x); acc.y = fmaf(xv.y, nrm, acc.y);
            acc.z = fmaf(xv.z, nrm, acc.z); acc.w = fmaf(xv.w, nrm, acc.w);
        }
    }
#pragma unroll
    for (int off = 16; off <= 32; off <<= 1) {
        acc.x += __shfl_xor(acc.x, off, 64);
        acc.y += __shfl_xor(acc.y, off, 64);
        acc.z += __shfl_xor(acc.z, off, 64);
        acc.w += __shfl_xor(acc.w, off, 64);
    }
    if (eg == 0) *(float4*)&agg[(size_t)v * D + dg * 4] = acc;
}

// ---------- dense GEMM + relu + W2-dot: wave per node, 16 nodes/wave ----------
#define NPW 16
__global__ __launch_bounds__(256) void k_gemm(
        const float* __restrict__ agg, const float* __restrict__ dinv,
        const float* __restrict__ W1, const float* __restrict__ b1,
        const float* __restrict__ W2, float* __restrict__ sd, int n) {
    __shared__ float lrow[4][D];
    int tid = threadIdx.x;
    int wave = tid >> 6, lane = tid & 63;
    float w1c[D];
#pragma unroll
    for (int d = 0; d < D; ++d) w1c[d] = W1[d * D + lane];
    float b1l = b1[lane], w2l = W2[lane];
    int v0 = (blockIdx.x * 4 + wave) * NPW;
    for (int k = 0; k < NPW; ++k) {
        int v = v0 + k;
        if (v >= n) break;
        lrow[wave][lane] = agg[(size_t)v * D + lane];  // coalesced 256B
        __builtin_amdgcn_wave_barrier();
        float h = b1l;
#pragma unroll
        for (int db = 0; db < D; db += 4) {
            float4 r = *(const float4*)&lrow[wave][db];  // broadcast ds_read_b128
            h = fmaf(r.x, w1c[db], h);
            h = fmaf(r.y, w1c[db + 1], h);
            h = fmaf(r.z, w1c[db + 2], h);
            h = fmaf(r.w, w1c[db + 3], h);
        }
        float tt = fmaxf(h, 0.0f) * w2l;
#pragma unroll
        for (int off = 1; off <= 32; off <<= 1) tt += __shfl_xor(tt, off, 64);
        if (lane == 0) sd[v] = tt * dinv[v];  // s[v] * dinv[v]
        __builtin_amdgcn_wave_barrier();
    }
}

// ---------- layer-2: 4 lanes per node gather over CSR ----------
__global__ __launch_bounds__(256) void k_out(const float* __restrict__ sd,
        const float* __restrict__ dinv, const int* __restrict__ row_ptr,
        const int* __restrict__ csr_src, const float* __restrict__ b2,
        float* __restrict__ out, int n) {
    int t = blockIdx.x * blockDim.x + threadIdx.x;
    int v = t >> 2, r = t & 3;
    if (v >= n) return;
    int beg = row_ptr[v], end = row_ptr[v + 1];
    float a = (r == 0) ? sd[v] : 0.0f;  // self-loop
    for (int i = beg + r; i < end; i += 4) a += sd[csr_src[i]];
    a += __shfl_xor(a, 1, 64);
    a += __shfl_xor(a, 2, 64);
    if (r == 0) out[v] = b2[0] + a * dinv[v];
}

extern "C" void kernel_launch(void* const* d_in, const int* in_sizes, int n_in,
                              void* d_out, int out_size, void* d_ws, size_t ws_size,
                              hipStream_t stream) {
    const float* x  = (const float*)d_in[0];
    const int*   ei = (const int*)d_in[1];
    const float* W1 = (const float*)d_in[2];
    const float* b1 = (const float*)d_in[3];
    const float* W2 = (const float*)d_in[4];
    const float* b2 = (const float*)d_in[5];

    int n = in_sizes[0] / D;   // 50000
    int E = in_sizes[1] / 2;   // 800000
    const int* src = ei;
    const int* dst = ei + E;

    char* ws = (char*)d_ws;
    auto take = [&](size_t bytes) {
        char* p = ws;
        ws += (bytes + 255) & ~(size_t)255;
        return p;
    };
    int nb = (n + 255) / 256;  // 196
    int*   deg     = (int*)take((size_t)n * sizeof(int));
    float* dinv    = (float*)take((size_t)n * sizeof(float));
    float* sd      = (float*)take((size_t)n * sizeof(float));
    int*   row_ptr = (int*)take((size_t)(n + 1) * sizeof(int));
    int*   bsum    = (int*)take((size_t)nb * sizeof(int));
    int*   rank    = (int*)take((size_t)E * sizeof(int));
    int*   csr_src = (int*)take((size_t)E * sizeof(int));
    float* agg     = (float*)take((size_t)n * D * sizeof(float));

    float* out = (float*)d_out;
    const int B = 256;

    hipMemsetAsync(deg, 0, (size_t)n * sizeof(int), stream);
    k_deg_count<<<(E / 4 + B - 1) / B, B, 0, stream>>>(dst, E, deg, rank);

    k_scan_partial<<<nb, 256, 0, stream>>>(deg, n, bsum, dinv);
    k_scan_bsum<<<1, 256, 0, stream>>>(bsum, nb);
    k_scan_final<<<nb, 256, 0, stream>>>(deg, n, bsum, row_ptr);

    k_bucket<<<((E + 1) / 2 + B - 1) / B, B, 0, stream>>>(src, dst, rank, E,
                                                          row_ptr, csr_src);

    k_gather<<<(n + 3) / 4, 256, 0, stream>>>(x, dinv, row_ptr, csr_src, agg, n);

    k_gemm<<<(n + 4 * NPW - 1) / (4 * NPW), 256, 0, stream>>>(agg, dinv, W1, b1,
                                                              W2, sd, n);

    k_out<<<((size_t)n * 4 + B - 1) / B, B, 0, stream>>>(sd, dinv, row_ptr, csr_src,
                                                         b2, out, n);
}